// Round 4
// baseline (286.835 us; speedup 1.0000x reference)
//
#include <hip/hip_runtime.h>
#include <hip/hip_bf16.h>

// RelativeAttention B=2,N=1024,C=512,H=8,HD=64 — round 3: pipelined attn.
//  attn_mfma: block=(b, i-tile16, jsplit2) = 256 blocks; 8 waves = 8 heads.
//  16-j tiles, double-buffered LDS, depth-2 register prefetch:
//    iter t: issue loads(t+2) -> write buf[(t+1)&1] (counted vmcnt) -> compute t
//  K=32 MFMAs with zero-padded P upper half (0 * clamped-valid B = 0).
//  3 barriers/iter: S2s-ready, P-ready, end (protects buffer swap).
// ws: qh 2MB | kh 2MB | vhT 2MB | xpart 8MB | lsum 128KB | xb 4MB

typedef __attribute__((ext_vector_type(8))) short short8;
typedef __attribute__((ext_vector_type(4))) float f32x4;

__device__ __forceinline__ unsigned short f2b(float f) {
    union { float f; unsigned u; } v; v.f = f;
    unsigned r = (v.u + 0x7FFF + ((v.u >> 16) & 1)) >> 16;   // RNE
    return (unsigned short)r;
}

// ---------------------------------------------------------------------------
// GEMM: Y = X[2048,512] @ W[512,512]   (unchanged from round 2)
// ---------------------------------------------------------------------------
template <int MODE>
__global__ __launch_bounds__(256) void gemm512(
    const float* __restrict__ X, const float* __restrict__ W,
    const float* __restrict__ bias, float* __restrict__ Yf,
    unsigned short* __restrict__ Ybf, float scale)
{
    __shared__ float As[32][68];
    __shared__ float Bs[32][68];
    __shared__ float Ts[(MODE == 2) ? 64 : 1][65];
    const int t  = threadIdx.x;
    const int tx = t & 15, ty = t >> 4;
    const int m0 = blockIdx.x * 64;
    const int n0 = blockIdx.y * 64;

    float acc[4][4] = {};

    for (int k0 = 0; k0 < 512; k0 += 32) {
        #pragma unroll
        for (int l = 0; l < 2; l++) {
            int qi = t + l * 256;
            int r = qi >> 3, q = qi & 7;
            float4 av = *reinterpret_cast<const float4*>(
                X + (size_t)(m0 + r) * 512 + k0 + q * 4);
            As[q * 4 + 0][r] = av.x; As[q * 4 + 1][r] = av.y;
            As[q * 4 + 2][r] = av.z; As[q * 4 + 3][r] = av.w;
        }
        #pragma unroll
        for (int l = 0; l < 2; l++) {
            int qi = t + l * 256;
            int kk = qi >> 4, q = qi & 15;
            *reinterpret_cast<float4*>(&Bs[kk][q * 4]) =
                *reinterpret_cast<const float4*>(
                    W + (size_t)(k0 + kk) * 512 + n0 + q * 4);
        }
        __syncthreads();
        #pragma unroll
        for (int kk = 0; kk < 32; kk++) {
            float4 a4 = *reinterpret_cast<const float4*>(&As[kk][ty * 4]);
            float4 b4 = *reinterpret_cast<const float4*>(&Bs[kk][tx * 4]);
            float av[4] = {a4.x, a4.y, a4.z, a4.w};
            float bv[4] = {b4.x, b4.y, b4.z, b4.w};
            #pragma unroll
            for (int ii = 0; ii < 4; ii++)
                #pragma unroll
                for (int jj = 0; jj < 4; jj++)
                    acc[ii][jj] = fmaf(av[ii], bv[jj], acc[ii][jj]);
        }
        __syncthreads();
    }

    if (MODE == 0) {
        const int h = n0 >> 6;
        #pragma unroll
        for (int ii = 0; ii < 4; ii++) {
            int m = m0 + ty * 4 + ii;
            int bb = m >> 10, nn = m & 1023;
            ushort4 o;
            o.x = f2b(acc[ii][0] * scale); o.y = f2b(acc[ii][1] * scale);
            o.z = f2b(acc[ii][2] * scale); o.w = f2b(acc[ii][3] * scale);
            *reinterpret_cast<ushort4*>(
                Ybf + ((size_t)((bb * 8 + h) * 1024 + nn)) * 64 + tx * 4) = o;
        }
    } else if (MODE == 1) {
        float4 bv = *reinterpret_cast<const float4*>(bias + n0 + tx * 4);
        #pragma unroll
        for (int ii = 0; ii < 4; ii++) {
            int m = m0 + ty * 4 + ii;
            float4 o;
            o.x = acc[ii][0] + bv.x; o.y = acc[ii][1] + bv.y;
            o.z = acc[ii][2] + bv.z; o.w = acc[ii][3] + bv.w;
            *reinterpret_cast<float4*>(Yf + (size_t)m * 512 + n0 + tx * 4) = o;
        }
    } else {
        #pragma unroll
        for (int ii = 0; ii < 4; ii++)
            #pragma unroll
            for (int jj = 0; jj < 4; jj++)
                Ts[ty * 4 + ii][tx * 4 + jj] = acc[ii][jj];
        __syncthreads();
        const int h = n0 >> 6;
        const int bb = m0 >> 10, nn = m0 & 1023;
        const int rc = t >> 2, jc = t & 3;
        unsigned short tmp[16];
        #pragma unroll
        for (int q = 0; q < 16; q++) tmp[q] = f2b(Ts[jc * 16 + q][rc]);
        unsigned short* dst = Ybf + (((size_t)(bb * 8 + h) * 64 + rc) << 10) + nn + jc * 16;
        *reinterpret_cast<short8*>(dst)     = *reinterpret_cast<short8*>(&tmp[0]);
        *reinterpret_cast<short8*>(dst + 8) = *reinterpret_cast<short8*>(&tmp[8]);
    }
}

// ---------------------------------------------------------------------------
// attn: grid 256 = b(2) x itile(64) x jsplit(2); 512 threads = 8 waves = heads
// ---------------------------------------------------------------------------
__global__ __launch_bounds__(512) void attn_mfma(
    const unsigned short* __restrict__ qhg, const unsigned short* __restrict__ khg,
    const unsigned short* __restrict__ vtg, const float* __restrict__ rpb,
    const float* __restrict__ mask, float* __restrict__ xpart,
    float* __restrict__ lsump)
{
    __shared__ unsigned short q1[8][16][72];        // [h][i][c]
    __shared__ unsigned short rpb_s[2][16][16][72]; // [buf][i][j][c]
    __shared__ unsigned short P[8][16][40];         // [h][i][j] j16..39 stay ZERO
    __shared__ float S2s[16][8][17];                // [i][h][j]

    const int bid = blockIdx.x;
    const int js = bid & 1, it = (bid >> 1) & 63, b = bid >> 7;
    const int i0 = it * 16, jb = js * 512;
    const int t = threadIdx.x, w = t >> 6, l = t & 63;
    const int lg = l >> 4, l16 = l & 15;

    // staging map: per itr 0..3, thread covers (i = sib+4*itr, j = sj, c = sc..sc+7)
    const int sj = (t >> 3) & 15, sc = (t & 7) * 8, sib = t >> 7;
    const float* rpbb = rpb + ((size_t)(b * 1024 + i0) << 16);

#define RPB_ISSUE(PF, J0)                                                      \
    _Pragma("unroll")                                                          \
    for (int itr = 0; itr < 4; ++itr) {                                        \
        const float4* s_ = reinterpret_cast<const float4*>(                    \
            rpbb + ((size_t)(sib + 4 * itr) << 16) +                           \
            (size_t)((J0) + sj) * 64 + sc);                                    \
        PF[2 * itr] = s_[0]; PF[2 * itr + 1] = s_[1];                          \
    }

#define RPB_WRITE(PF, BUF)                                                     \
    _Pragma("unroll")                                                          \
    for (int itr = 0; itr < 4; ++itr) {                                        \
        float4 ua = PF[2 * itr], ub = PF[2 * itr + 1];                         \
        short8 pk;                                                             \
        pk[0] = (short)f2b(ua.x); pk[1] = (short)f2b(ua.y);                    \
        pk[2] = (short)f2b(ua.z); pk[3] = (short)f2b(ua.w);                    \
        pk[4] = (short)f2b(ub.x); pk[5] = (short)f2b(ub.y);                    \
        pk[6] = (short)f2b(ub.z); pk[7] = (short)f2b(ub.w);                    \
        *reinterpret_cast<short8*>(&rpb_s[BUF][sib + 4 * itr][sj][sc]) = pk;   \
    }

    // ---- prologue: q tile, zero P, prefetch tiles 0,1 ----
    {
        int h = t >> 6, i = (t >> 2) & 15, c = (t & 3) * 16;
        const short8* src = reinterpret_cast<const short8*>(
            qhg + (((size_t)(b * 8 + h) * 1024 + i0 + i) << 6) + c);
        *reinterpret_cast<short8*>(&q1[h][i][c])     = src[0];
        *reinterpret_cast<short8*>(&q1[h][i][c + 8]) = src[1];
    }
    {
        unsigned short* P1 = &P[0][0][0];
        #pragma unroll
        for (int r = 0; r < 10; ++r) P1[t + 512 * r] = 0;   // 5120 = 512*10
    }

    float4 pf0[8], pf1[8];
    RPB_ISSUE(pf0, jb)          // tile 0
    RPB_WRITE(pf0, 0)           // buf0 (drains pf0)
    RPB_ISSUE(pf1, jb + 16)     // tile 1
    __syncthreads();            // q1 + P-zero + buf0 visible

    // ---- hoisted loop-invariant fragments ----
    short8 a1[2];
    a1[0] = *reinterpret_cast<const short8*>(&q1[w][l16][8 * lg]);
    a1[1] = *reinterpret_cast<const short8*>(&q1[w][l16][32 + 8 * lg]);
    short8 bq[2][2];
    #pragma unroll
    for (int il = 0; il < 2; ++il)
        #pragma unroll
        for (int ch = 0; ch < 2; ++ch)
            bq[il][ch] = *reinterpret_cast<const short8*>(
                &q1[l16 & 7][2 * w + il][ch * 32 + 8 * lg]);

    float mrow[4];
    #pragma unroll
    for (int r = 0; r < 4; r++) mrow[r] = mask[b * 1024 + i0 + lg * 4 + r];

    const unsigned short* khb = khg + ((size_t)(b * 8 + w) << 16);
    const unsigned short* vtb = vtg + ((size_t)(b * 8 + w) << 16);
    const int jo = (lg < 2) ? 8 * lg : 0;   // clamp for zero-padded K half
    const int ro = jo;

    f32x4 x1[4];
    #pragma unroll
    for (int cs = 0; cs < 4; cs++) x1[cs] = 0.0f;
    f32x4 x2[2][4];
    #pragma unroll
    for (int il = 0; il < 2; il++)
        #pragma unroll
        for (int cg = 0; cg < 4; cg++) x2[il][cg] = 0.0f;
    float lsum[4] = {0.f, 0.f, 0.f, 0.f};

#define ATTN_ITER(T, PFW, PFI)                                                 \
    {                                                                          \
        const int tcur = (T);                                                  \
        const int cur = tcur & 1;                                              \
        const int j0 = jb + tcur * 16;                                         \
        if (tcur < 30) { RPB_ISSUE(PFI, j0 + 32) }                             \
        if (tcur < 31) { RPB_WRITE(PFW, cur ^ 1) }                             \
        float mj = mask[b * 1024 + j0 + l16];                                  \
        /* S1 = QK^T : D[16i x 16j], K=64 */                                   \
        f32x4 C1; C1 = 0.0f;                                                   \
        _Pragma("unroll")                                                      \
        for (int ch = 0; ch < 2; ++ch) {                                       \
            short8 kb = *reinterpret_cast<const short8*>(                      \
                khb + (((size_t)(j0 + l16)) << 6) + ch * 32 + 8 * lg);         \
            C1 = __builtin_amdgcn_mfma_f32_16x16x32_bf16(a1[ch], kb, C1, 0, 0, 0); \
        }                                                                      \
        /* S2^T = rpb(A) @ q(B) : D[16j x 8h] per i */                         \
        _Pragma("unroll")                                                      \
        for (int il = 0; il < 2; ++il) {                                       \
            int i = 2 * w + il;                                                \
            f32x4 D2; D2 = 0.0f;                                               \
            _Pragma("unroll")                                                  \
            for (int ch = 0; ch < 2; ++ch) {                                   \
                short8 ar = *reinterpret_cast<const short8*>(                  \
                    &rpb_s[cur][i][l16][ch * 32 + 8 * lg]);                    \
                D2 = __builtin_amdgcn_mfma_f32_16x16x32_bf16(ar, bq[il][ch], D2, 0, 0, 0); \
            }                                                                  \
            if (l16 < 8) {                                                     \
                _Pragma("unroll")                                              \
                for (int r = 0; r < 4; ++r)                                    \
                    S2s[i][l16][4 * lg + r] = D2[r];                           \
            }                                                                  \
        }                                                                      \
        __syncthreads();  /* S2s ready */                                      \
        /* P = exp(S1 + S2 + pairmask) */                                      \
        _Pragma("unroll")                                                      \
        for (int r = 0; r < 4; ++r) {                                          \
            int ir = lg * 4 + r;                                               \
            float mi = mrow[r];                                                \
            float pm = (fmaxf(mi, mj) < 0.f) ? 0.f : fminf(mi, mj);            \
            float s = C1[r] + S2s[ir][w][l16] + pm;                            \
            float p = __expf(s);                                               \
            lsum[r] += p;                                                      \
            P[w][ir][l16] = f2b(p);                                            \
        }                                                                      \
        __syncthreads();  /* P ready */                                        \
        /* X1 += P @ vhT : D[16i x 64c] (upper K zero-padded) */               \
        {                                                                      \
            short8 pa = *reinterpret_cast<const short8*>(&P[w][l16][8 * lg]);  \
            _Pragma("unroll")                                                  \
            for (int cs = 0; cs < 4; ++cs) {                                   \
                short8 vb = *reinterpret_cast<const short8*>(                  \
                    vtb + ((size_t)(cs * 16 + l16) << 10) + j0 + jo);          \
                x1[cs] = __builtin_amdgcn_mfma_f32_16x16x32_bf16(pa, vb, x1[cs], 0, 0, 0); \
            }                                                                  \
        }                                                                      \
        /* X2 += P(A) @ rpb(B) : D[8h x 16c] per i */                          \
        _Pragma("unroll")                                                      \
        for (int il = 0; il < 2; ++il) {                                       \
            int i = 2 * w + il;                                                \
            short8 pa2 = *reinterpret_cast<const short8*>(&P[l16 & 7][i][8 * lg]); \
            _Pragma("unroll")                                                  \
            for (int cg = 0; cg < 4; ++cg) {                                   \
                short8 bb;                                                     \
                _Pragma("unroll")                                              \
                for (int e = 0; e < 8; ++e)                                    \
                    bb[e] = (short)rpb_s[cur][i][ro + e][cg * 16 + l16];       \
                x2[il][cg] = __builtin_amdgcn_mfma_f32_16x16x32_bf16(pa2, bb, x2[il][cg], 0, 0, 0); \
            }                                                                  \
        }                                                                      \
        __syncthreads();  /* end: protects buffer swap + P/S2s reuse */        \
    }

    for (int th = 0; th < 16; ++th) {
        ATTN_ITER(2 * th,     pf1, pf0)
        ATTN_ITER(2 * th + 1, pf0, pf1)
    }

    // ---- epilogue ----
    #pragma unroll
    for (int r = 0; r < 4; ++r) {
        float v = lsum[r];
        v += __shfl_xor(v, 1, 64); v += __shfl_xor(v, 2, 64);
        v += __shfl_xor(v, 4, 64); v += __shfl_xor(v, 8, 64);
        lsum[r] = v;
    }

    // redistribute x2 through LDS (reuse rpb_s; all reads done after end-bar)
    float* x2s = reinterpret_cast<float*>(&rpb_s[0][0][0][0]);  // [16i][8h][64c]
    if (lg < 2) {
        #pragma unroll
        for (int il = 0; il < 2; ++il)
            #pragma unroll
            for (int cg = 0; cg < 4; ++cg)
                #pragma unroll
                for (int r = 0; r < 4; ++r)
                    x2s[((2 * w + il) * 8 + 4 * lg + r) * 64 + cg * 16 + l16] =
                        x2[il][cg][r];
    }
    __syncthreads();

    #pragma unroll
    for (int cs = 0; cs < 4; ++cs)
        #pragma unroll
        for (int r = 0; r < 4; ++r) {
            int ir = lg * 4 + r;
            float val = x1[cs][r] + x2s[(ir * 8 + w) * 64 + cs * 16 + l16];
            xpart[((size_t)js << 20) + ((size_t)(b * 1024 + i0 + ir)) * 512
                  + w * 64 + cs * 16 + l16] = val;
        }
    if (l16 == 0) {
        #pragma unroll
        for (int r = 0; r < 4; ++r)
            lsump[((size_t)js << 14) + (b * 8 + w) * 1024 + i0 + lg * 4 + r] = lsum[r];
    }
#undef ATTN_ITER
#undef RPB_ISSUE
#undef RPB_WRITE
}

// ---------------------------------------------------------------------------
__global__ __launch_bounds__(256) void combine(
    const float* __restrict__ xpart, const float* __restrict__ lsump,
    float* __restrict__ xb)
{
    int idx4 = blockIdx.x * 256 + threadIdx.x;
    size_t base = (size_t)idx4 * 4;
    int row = (int)(base >> 9), col = (int)(base & 511);
    int bb = row >> 10, n = row & 1023, h = col >> 6;
    float ax = 0.f, ay = 0.f, az = 0.f, aw = 0.f, ls = 0.f;
    #pragma unroll
    for (int js = 0; js < 2; ++js) {
        float4 v = *reinterpret_cast<const float4*>(xpart + ((size_t)js << 20) + base);
        ax += v.x; ay += v.y; az += v.z; aw += v.w;
        ls += lsump[(js << 14) + (bb * 8 + h) * 1024 + n];
    }
    float inv = 1.f / ls;
    float4 o; o.x = ax * inv; o.y = ay * inv; o.z = az * inv; o.w = aw * inv;
    *reinterpret_cast<float4*>(xb + base) = o;
}

// ---------------------------------------------------------------------------
extern "C" void kernel_launch(void* const* d_in, const int* in_sizes, int n_in,
                              void* d_out, int out_size, void* d_ws, size_t ws_size,
                              hipStream_t stream)
{
    (void)in_sizes; (void)n_in; (void)out_size; (void)ws_size;
    const float* q    = (const float*)d_in[0];
    const float* k    = (const float*)d_in[1];
    const float* v    = (const float*)d_in[2];
    const float* rpb  = (const float*)d_in[3];
    const float* mask = (const float*)d_in[4];
    const float* Wq   = (const float*)d_in[5];
    const float* Wk   = (const float*)d_in[6];
    const float* Wv   = (const float*)d_in[7];
    const float* Wp   = (const float*)d_in[8];
    const float* bp   = (const float*)d_in[9];
    float* out = (float*)d_out;

    unsigned short* qhb = (unsigned short*)d_ws;     // bf16 [2,8,1024,64]
    unsigned short* khb = qhb + 1048576;
    unsigned short* vtb = khb + 1048576;             // bf16 [2,8,64,1024]
    float* xpart = (float*)(vtb + 1048576);          // [2][2048][512]
    float* lsump = xpart + 2097152;                  // [2][16][1024]
    float* xb    = lsump + 32768;                    // [2048][512]

    dim3 gg(32, 8, 1);
    gemm512<0><<<gg, 256, 0, stream>>>(q, Wq, nullptr, nullptr, qhb, 0.125f);
    gemm512<0><<<gg, 256, 0, stream>>>(k, Wk, nullptr, nullptr, khb, 1.0f);
    gemm512<2><<<gg, 256, 0, stream>>>(v, Wv, nullptr, nullptr, vtb, 1.0f);

    attn_mfma<<<256, 512, 0, stream>>>(qhb, khb, vtb, rpb, mask, xpart, lsump);

    combine<<<1024, 256, 0, stream>>>(xpart, lsump, xb);

    gemm512<1><<<gg, 256, 0, stream>>>(xb, Wp, bp, out, nullptr, 1.0f);
}

// Round 5
// 281.177 us; speedup vs baseline: 1.0201x; 1.0201x over previous
//
#include <hip/hip_runtime.h>
#include <hip/hip_bf16.h>

// RelativeAttention B=2,N=1024,C=512,H=8,HD=64 — round 4: raw barriers.
//  Same dataflow as round 3 (passed, absmax 1.95e-3), but in-loop
//  __syncthreads() replaced by {s_waitcnt lgkmcnt(0); s_barrier} so global
//  prefetches stay in flight across barriers (T3/T4). All in-loop global
//  consumption (rpb, kh, mask, vtb) is prefetched in issue order matching
//  consume order so counted vmcnt never drains the pipeline.
// ws: qh 2MB | kh 2MB | vhT 2MB | xpart 8MB | lsum 128KB | xb 4MB

typedef __attribute__((ext_vector_type(8))) short short8;
typedef __attribute__((ext_vector_type(4))) float f32x4;

__device__ __forceinline__ unsigned short f2b(float f) {
    union { float f; unsigned u; } v; v.f = f;
    unsigned r = (v.u + 0x7FFF + ((v.u >> 16) & 1)) >> 16;   // RNE
    return (unsigned short)r;
}

// lgkm-drain + raw barrier: LDS ops ordered, global loads NOT drained.
#define LGKM0_BAR()                                            \
    do {                                                       \
        asm volatile("s_waitcnt lgkmcnt(0)" ::: "memory");     \
        __builtin_amdgcn_s_barrier();                          \
        asm volatile("" ::: "memory");                         \
    } while (0)

// ---------------------------------------------------------------------------
// GEMM: Y = X[2048,512] @ W[512,512]   (unchanged)
// ---------------------------------------------------------------------------
template <int MODE>
__global__ __launch_bounds__(256) void gemm512(
    const float* __restrict__ X, const float* __restrict__ W,
    const float* __restrict__ bias, float* __restrict__ Yf,
    unsigned short* __restrict__ Ybf, float scale)
{
    __shared__ float As[32][68];
    __shared__ float Bs[32][68];
    __shared__ float Ts[(MODE == 2) ? 64 : 1][65];
    const int t  = threadIdx.x;
    const int tx = t & 15, ty = t >> 4;
    const int m0 = blockIdx.x * 64;
    const int n0 = blockIdx.y * 64;

    float acc[4][4] = {};

    for (int k0 = 0; k0 < 512; k0 += 32) {
        #pragma unroll
        for (int l = 0; l < 2; l++) {
            int qi = t + l * 256;
            int r = qi >> 3, q = qi & 7;
            float4 av = *reinterpret_cast<const float4*>(
                X + (size_t)(m0 + r) * 512 + k0 + q * 4);
            As[q * 4 + 0][r] = av.x; As[q * 4 + 1][r] = av.y;
            As[q * 4 + 2][r] = av.z; As[q * 4 + 3][r] = av.w;
        }
        #pragma unroll
        for (int l = 0; l < 2; l++) {
            int qi = t + l * 256;
            int kk = qi >> 4, q = qi & 15;
            *reinterpret_cast<float4*>(&Bs[kk][q * 4]) =
                *reinterpret_cast<const float4*>(
                    W + (size_t)(k0 + kk) * 512 + n0 + q * 4);
        }
        __syncthreads();
        #pragma unroll
        for (int kk = 0; kk < 32; kk++) {
            float4 a4 = *reinterpret_cast<const float4*>(&As[kk][ty * 4]);
            float4 b4 = *reinterpret_cast<const float4*>(&Bs[kk][tx * 4]);
            float av[4] = {a4.x, a4.y, a4.z, a4.w};
            float bv[4] = {b4.x, b4.y, b4.z, b4.w};
            #pragma unroll
            for (int ii = 0; ii < 4; ii++)
                #pragma unroll
                for (int jj = 0; jj < 4; jj++)
                    acc[ii][jj] = fmaf(av[ii], bv[jj], acc[ii][jj]);
        }
        __syncthreads();
    }

    if (MODE == 0) {
        const int h = n0 >> 6;
        #pragma unroll
        for (int ii = 0; ii < 4; ii++) {
            int m = m0 + ty * 4 + ii;
            int bb = m >> 10, nn = m & 1023;
            ushort4 o;
            o.x = f2b(acc[ii][0] * scale); o.y = f2b(acc[ii][1] * scale);
            o.z = f2b(acc[ii][2] * scale); o.w = f2b(acc[ii][3] * scale);
            *reinterpret_cast<ushort4*>(
                Ybf + ((size_t)((bb * 8 + h) * 1024 + nn)) * 64 + tx * 4) = o;
        }
    } else if (MODE == 1) {
        float4 bv = *reinterpret_cast<const float4*>(bias + n0 + tx * 4);
        #pragma unroll
        for (int ii = 0; ii < 4; ii++) {
            int m = m0 + ty * 4 + ii;
            float4 o;
            o.x = acc[ii][0] + bv.x; o.y = acc[ii][1] + bv.y;
            o.z = acc[ii][2] + bv.z; o.w = acc[ii][3] + bv.w;
            *reinterpret_cast<float4*>(Yf + (size_t)m * 512 + n0 + tx * 4) = o;
        }
    } else {
        #pragma unroll
        for (int ii = 0; ii < 4; ii++)
            #pragma unroll
            for (int jj = 0; jj < 4; jj++)
                Ts[ty * 4 + ii][tx * 4 + jj] = acc[ii][jj];
        __syncthreads();
        const int h = n0 >> 6;
        const int bb = m0 >> 10, nn = m0 & 1023;
        const int rc = t >> 2, jc = t & 3;
        unsigned short tmp[16];
        #pragma unroll
        for (int q = 0; q < 16; q++) tmp[q] = f2b(Ts[jc * 16 + q][rc]);
        unsigned short* dst = Ybf + (((size_t)(bb * 8 + h) * 64 + rc) << 10) + nn + jc * 16;
        *reinterpret_cast<short8*>(dst)     = *reinterpret_cast<short8*>(&tmp[0]);
        *reinterpret_cast<short8*>(dst + 8) = *reinterpret_cast<short8*>(&tmp[8]);
    }
}

// ---------------------------------------------------------------------------
// attn: grid 256 = b(2) x itile(64) x jsplit(2); 512 threads = 8 waves = heads
// ---------------------------------------------------------------------------
__global__ __launch_bounds__(512) void attn_mfma(
    const unsigned short* __restrict__ qhg, const unsigned short* __restrict__ khg,
    const unsigned short* __restrict__ vtg, const float* __restrict__ rpb,
    const float* __restrict__ mask, float* __restrict__ xpart,
    float* __restrict__ lsump)
{
    __shared__ unsigned short q1[8][16][72];        // [h][i][c]
    __shared__ unsigned short rpb_s[2][16][16][72]; // [buf][i][j][c]
    __shared__ unsigned short P[8][16][40];         // [h][i][j] j16..39 stay ZERO
    __shared__ float S2s[16][8][17];                // [i][h][j]

    const int bid = blockIdx.x;
    const int js = bid & 1, it = (bid >> 1) & 63, b = bid >> 7;
    const int i0 = it * 16, jb = js * 512;
    const int t = threadIdx.x, w = t >> 6, l = t & 63;
    const int lg = l >> 4, l16 = l & 15;

    // staging map: per itr 0..3, thread covers (i = sib+4*itr, j = sj, c = sc..+7)
    const int sj = (t >> 3) & 15, sc = (t & 7) * 8, sib = t >> 7;
    const float* rpbb = rpb + ((size_t)(b * 1024 + i0) << 16);
    const unsigned short* khb = khg + ((size_t)(b * 8 + w) << 16);
    const unsigned short* vtb = vtg + ((size_t)(b * 8 + w) << 16);

#define RPB_ISSUE(PF, J0)                                                      \
    _Pragma("unroll")                                                          \
    for (int itr = 0; itr < 4; ++itr) {                                        \
        const float4* s_ = reinterpret_cast<const float4*>(                    \
            rpbb + ((size_t)(sib + 4 * itr) << 16) +                           \
            (size_t)((J0) + sj) * 64 + sc);                                    \
        PF[2 * itr] = s_[0]; PF[2 * itr + 1] = s_[1];                          \
    }

#define RPB_WRITE(PF, BUF)                                                     \
    _Pragma("unroll")                                                          \
    for (int itr = 0; itr < 4; ++itr) {                                        \
        float4 ua = PF[2 * itr], ub = PF[2 * itr + 1];                         \
        short8 pk;                                                             \
        pk[0] = (short)f2b(ua.x); pk[1] = (short)f2b(ua.y);                    \
        pk[2] = (short)f2b(ua.z); pk[3] = (short)f2b(ua.w);                    \
        pk[4] = (short)f2b(ub.x); pk[5] = (short)f2b(ub.y);                    \
        pk[6] = (short)f2b(ub.z); pk[7] = (short)f2b(ub.w);                    \
        *reinterpret_cast<short8*>(&rpb_s[BUF][sib + 4 * itr][sj][sc]) = pk;   \
    }

#define K_ISSUE(KPF, J0)                                                       \
    {                                                                          \
        const unsigned short* kp_ = khb + (((size_t)((J0) + l16)) << 6) + 8 * lg; \
        KPF[0] = *reinterpret_cast<const short8*>(kp_);                        \
        KPF[1] = *reinterpret_cast<const short8*>(kp_ + 32);                   \
    }

    // ---- prologue ----
    {
        int h = t >> 6, i = (t >> 2) & 15, c = (t & 3) * 16;
        const short8* src = reinterpret_cast<const short8*>(
            qhg + (((size_t)(b * 8 + h) * 1024 + i0 + i) << 6) + c);
        *reinterpret_cast<short8*>(&q1[h][i][c])     = src[0];
        *reinterpret_cast<short8*>(&q1[h][i][c + 8]) = src[1];
    }
    {
        unsigned short* P1 = &P[0][0][0];
        #pragma unroll
        for (int r = 0; r < 10; ++r) P1[t + 512 * r] = 0;   // 5120 = 512*10
    }

    float4 pf0[8], pf1[8];
    short8 kpf0[2], kpf1[2];
    float mj0, mj1;

    RPB_ISSUE(pf0, jb)                       // tile 0
    K_ISSUE(kpf0, jb)
    mj0 = mask[b * 1024 + jb + l16];
    RPB_WRITE(pf0, 0)                        // waits pf0 (counted), buf0
    RPB_ISSUE(pf1, jb + 16)                  // tile 1 — stays in flight
    K_ISSUE(kpf1, jb + 16)
    mj1 = mask[b * 1024 + jb + 16 + l16];

    float mrow[4];
    #pragma unroll
    for (int r = 0; r < 4; r++) mrow[r] = mask[b * 1024 + i0 + lg * 4 + r];

    LGKM0_BAR();                             // q1 + P-zero + buf0 visible

    // hoisted loop-invariant fragments (from q1 LDS)
    short8 a1[2];
    a1[0] = *reinterpret_cast<const short8*>(&q1[w][l16][8 * lg]);
    a1[1] = *reinterpret_cast<const short8*>(&q1[w][l16][32 + 8 * lg]);
    short8 bq[2][2];
    #pragma unroll
    for (int il = 0; il < 2; ++il)
        #pragma unroll
        for (int ch = 0; ch < 2; ++ch)
            bq[il][ch] = *reinterpret_cast<const short8*>(
                &q1[l16 & 7][2 * w + il][ch * 32 + 8 * lg]);

    const int jo = (lg < 2) ? 8 * lg : 0;    // clamp for zero-padded K half
    const int ro = jo;

    f32x4 x1[4];
    #pragma unroll
    for (int cs = 0; cs < 4; cs++) x1[cs] = 0.0f;
    f32x4 x2[2][4];
    #pragma unroll
    for (int il = 0; il < 2; il++)
        #pragma unroll
        for (int cg = 0; cg < 4; cg++) x2[il][cg] = 0.0f;
    float lsum[4] = {0.f, 0.f, 0.f, 0.f};

#define ATTN_ITER(T, PFA, KPFA, MJA, PFB)                                      \
    {                                                                          \
        const int tcur = (T);                                                  \
        const int cur = tcur & 1;                                              \
        const int j0 = jb + tcur * 16;                                         \
        /* consume this tile's prefetched kh/mask (issued at t-2, landed) */   \
        short8 skb0 = KPFA[0], skb1 = KPFA[1];                                 \
        float smj = MJA;                                                       \
        /* re-issue set A for tile t+2 (stays in flight across barriers) */    \
        if (tcur < 30) {                                                       \
            RPB_ISSUE(PFA, j0 + 32)                                            \
            K_ISSUE(KPFA, j0 + 32)                                             \
            MJA = mask[b * 1024 + j0 + 32 + l16];                              \
        }                                                                      \
        /* vtb for THIS iter, issued early so its wait leaves t+2 in flight */ \
        short8 vb[4];                                                          \
        _Pragma("unroll")                                                      \
        for (int cs = 0; cs < 4; ++cs)                                         \
            vb[cs] = *reinterpret_cast<const short8*>(                         \
                vtb + ((size_t)(cs * 16 + l16) << 10) + j0 + jo);              \
        /* write tile t+1 into other buffer (counted vmcnt on PFB only) */     \
        if (tcur < 31) { RPB_WRITE(PFB, cur ^ 1) }                             \
        /* S1 = QK^T : D[16i x 16j], K=64 */                                   \
        f32x4 C1; C1 = 0.0f;                                                   \
        C1 = __builtin_amdgcn_mfma_f32_16x16x32_bf16(a1[0], skb0, C1, 0, 0, 0); \
        C1 = __builtin_amdgcn_mfma_f32_16x16x32_bf16(a1[1], skb1, C1, 0, 0, 0); \
        /* S2^T = rpb(A) @ q(B) : D[16j x 8h] per i */                         \
        _Pragma("unroll")                                                      \
        for (int il = 0; il < 2; ++il) {                                       \
            int i = 2 * w + il;                                                \
            f32x4 D2; D2 = 0.0f;                                               \
            _Pragma("unroll")                                                  \
            for (int ch = 0; ch < 2; ++ch) {                                   \
                short8 ar = *reinterpret_cast<const short8*>(                  \
                    &rpb_s[cur][i][l16][ch * 32 + 8 * lg]);                    \
                D2 = __builtin_amdgcn_mfma_f32_16x16x32_bf16(ar, bq[il][ch], D2, 0, 0, 0); \
            }                                                                  \
            if (l16 < 8) {                                                     \
                _Pragma("unroll")                                              \
                for (int r = 0; r < 4; ++r)                                    \
                    S2s[i][l16][4 * lg + r] = D2[r];                           \
            }                                                                  \
        }                                                                      \
        LGKM0_BAR();  /* S2s ready */                                          \
        /* P = exp(S1 + S2 + pairmask) */                                      \
        _Pragma("unroll")                                                      \
        for (int r = 0; r < 4; ++r) {                                          \
            int ir = lg * 4 + r;                                               \
            float mi = mrow[r];                                                \
            float pm = (fmaxf(mi, smj) < 0.f) ? 0.f : fminf(mi, smj);          \
            float s = C1[r] + S2s[ir][w][l16] + pm;                            \
            float p = __expf(s);                                               \
            lsum[r] += p;                                                      \
            P[w][ir][l16] = f2b(p);                                            \
        }                                                                      \
        LGKM0_BAR();  /* P ready */                                            \
        /* X1 += P @ vhT : D[16i x 64c] (upper K zero-padded) */               \
        {                                                                      \
            short8 pa = *reinterpret_cast<const short8*>(&P[w][l16][8 * lg]);  \
            _Pragma("unroll")                                                  \
            for (int cs = 0; cs < 4; ++cs)                                     \
                x1[cs] = __builtin_amdgcn_mfma_f32_16x16x32_bf16(pa, vb[cs], x1[cs], 0, 0, 0); \
        }                                                                      \
        /* X2 += P(A) @ rpb(B) : D[8h x 16c] per i */                          \
        _Pragma("unroll")                                                      \
        for (int il = 0; il < 2; ++il) {                                       \
            int i = 2 * w + il;                                                \
            short8 pa2 = *reinterpret_cast<const short8*>(&P[l16 & 7][i][8 * lg]); \
            _Pragma("unroll")                                                  \
            for (int cg = 0; cg < 4; ++cg) {                                   \
                short8 bb;                                                     \
                _Pragma("unroll")                                              \
                for (int e = 0; e < 8; ++e)                                    \
                    bb[e] = (short)rpb_s[cur][i][ro + e][cg * 16 + l16];       \
                x2[il][cg] = __builtin_amdgcn_mfma_f32_16x16x32_bf16(pa2, bb, x2[il][cg], 0, 0, 0); \
            }                                                                  \
        }                                                                      \
        LGKM0_BAR();  /* end: protects buffer swap + P/S2s reuse */            \
    }

    for (int th = 0; th < 16; ++th) {
        ATTN_ITER(2 * th,     pf0, kpf0, mj0, pf1)
        ATTN_ITER(2 * th + 1, pf1, kpf1, mj1, pf0)
    }

    // ---- epilogue ----
    #pragma unroll
    for (int r = 0; r < 4; ++r) {
        float v = lsum[r];
        v += __shfl_xor(v, 1, 64); v += __shfl_xor(v, 2, 64);
        v += __shfl_xor(v, 4, 64); v += __shfl_xor(v, 8, 64);
        lsum[r] = v;
    }

    // redistribute x2 through LDS (reuse rpb_s; all reads done after end-bar)
    float* x2s = reinterpret_cast<float*>(&rpb_s[0][0][0][0]);  // [16i][8h][64c]
    if (lg < 2) {
        #pragma unroll
        for (int il = 0; il < 2; ++il)
            #pragma unroll
            for (int cg = 0; cg < 4; ++cg)
                #pragma unroll
                for (int r = 0; r < 4; ++r)
                    x2s[((2 * w + il) * 8 + 4 * lg + r) * 64 + cg * 16 + l16] =
                        x2[il][cg][r];
    }
    __syncthreads();

    #pragma unroll
    for (int cs = 0; cs < 4; ++cs)
        #pragma unroll
        for (int r = 0; r < 4; ++r) {
            int ir = lg * 4 + r;
            float val = x1[cs][r] + x2s[(ir * 8 + w) * 64 + cs * 16 + l16];
            xpart[((size_t)js << 20) + ((size_t)(b * 1024 + i0 + ir)) * 512
                  + w * 64 + cs * 16 + l16] = val;
        }
    if (l16 == 0) {
        #pragma unroll
        for (int r = 0; r < 4; ++r)
            lsump[((size_t)js << 14) + (b * 8 + w) * 1024 + i0 + lg * 4 + r] = lsum[r];
    }
#undef ATTN_ITER
#undef RPB_ISSUE
#undef RPB_WRITE
#undef K_ISSUE
}

// ---------------------------------------------------------------------------
__global__ __launch_bounds__(256) void combine(
    const float* __restrict__ xpart, const float* __restrict__ lsump,
    float* __restrict__ xb)
{
    int idx4 = blockIdx.x * 256 + threadIdx.x;
    size_t base = (size_t)idx4 * 4;
    int row = (int)(base >> 9), col = (int)(base & 511);
    int bb = row >> 10, n = row & 1023, h = col >> 6;
    float ax = 0.f, ay = 0.f, az = 0.f, aw = 0.f, ls = 0.f;
    #pragma unroll
    for (int js = 0; js < 2; ++js) {
        float4 v = *reinterpret_cast<const float4*>(xpart + ((size_t)js << 20) + base);
        ax += v.x; ay += v.y; az += v.z; aw += v.w;
        ls += lsump[(js << 14) + (bb * 8 + h) * 1024 + n];
    }
    float inv = 1.f / ls;
    float4 o; o.x = ax * inv; o.y = ay * inv; o.z = az * inv; o.w = aw * inv;
    *reinterpret_cast<float4*>(xb + base) = o;
}

// ---------------------------------------------------------------------------
extern "C" void kernel_launch(void* const* d_in, const int* in_sizes, int n_in,
                              void* d_out, int out_size, void* d_ws, size_t ws_size,
                              hipStream_t stream)
{
    (void)in_sizes; (void)n_in; (void)out_size; (void)ws_size;
    const float* q    = (const float*)d_in[0];
    const float* k    = (const float*)d_in[1];
    const float* v    = (const float*)d_in[2];
    const float* rpb  = (const float*)d_in[3];
    const float* mask = (const float*)d_in[4];
    const float* Wq   = (const float*)d_in[5];
    const float* Wk   = (const float*)d_in[6];
    const float* Wv   = (const float*)d_in[7];
    const float* Wp   = (const float*)d_in[8];
    const float* bp   = (const float*)d_in[9];
    float* out = (float*)d_out;

    unsigned short* qhb = (unsigned short*)d_ws;     // bf16 [2,8,1024,64]
    unsigned short* khb = qhb + 1048576;
    unsigned short* vtb = khb + 1048576;             // bf16 [2,8,64,1024]
    float* xpart = (float*)(vtb + 1048576);          // [2][2048][512]
    float* lsump = xpart + 2097152;                  // [2][16][1024]
    float* xb    = lsump + 32768;                    // [2048][512]

    dim3 gg(32, 8, 1);
    gemm512<0><<<gg, 256, 0, stream>>>(q, Wq, nullptr, nullptr, qhb, 0.125f);
    gemm512<0><<<gg, 256, 0, stream>>>(k, Wk, nullptr, nullptr, khb, 1.0f);
    gemm512<2><<<gg, 256, 0, stream>>>(v, Wv, nullptr, nullptr, vtb, 1.0f);

    attn_mfma<<<256, 512, 0, stream>>>(qhb, khb, vtb, rpb, mask, xpart, lsump);

    combine<<<1024, 256, 0, stream>>>(xpart, lsump, xb);

    gemm512<1><<<gg, 256, 0, stream>>>(xb, Wp, bp, out, nullptr, 1.0f);
}

// Round 6
// 276.980 us; speedup vs baseline: 1.0356x; 1.0152x over previous
//
#include <hip/hip_runtime.h>
#include <hip/hip_bf16.h>

// RelativeAttention B=2,N=1024,C=512,H=8,HD=64 — round 5: occupancy fix.
//  attn: grid 512 = b(2) x itile(64) x jsplit(4) -> 2 blocks/CU (LDS 54.5KB),
//  4 waves/SIMD. No q1 LDS (q frags direct from global). Single-buffer 16-j
//  rpb tile, 4 __syncthreads/iter (r2-proven order). Staging converts via
//  v_cvt_pk_bf16_f32 (1 instr / 2 floats, RNE). __launch_bounds__(512,4).
// ws: qh 2MB | kh 2MB | vhT 2MB | xpart 16MB | lsum 256KB | xb 4MB

typedef __attribute__((ext_vector_type(8))) short short8;
typedef __attribute__((ext_vector_type(4))) float f32x4;

__device__ __forceinline__ unsigned short f2b(float f) {
    union { float f; unsigned u; } v; v.f = f;
    unsigned r = (v.u + 0x7FFF + ((v.u >> 16) & 1)) >> 16;   // RNE
    return (unsigned short)r;
}

// v_cvt_pk_bf16_f32: dst = [bf16(b) | bf16(a)] (RNE), 1 VALU op
__device__ __forceinline__ unsigned cvt_pk(float a, float b) {
    unsigned r;
    asm("v_cvt_pk_bf16_f32 %0, %1, %2" : "=v"(r) : "v"(a), "v"(b));
    return r;
}

// ---------------------------------------------------------------------------
// GEMM: Y = X[2048,512] @ W[512,512]   (unchanged)
// ---------------------------------------------------------------------------
template <int MODE>
__global__ __launch_bounds__(256) void gemm512(
    const float* __restrict__ X, const float* __restrict__ W,
    const float* __restrict__ bias, float* __restrict__ Yf,
    unsigned short* __restrict__ Ybf, float scale)
{
    __shared__ float As[32][68];
    __shared__ float Bs[32][68];
    __shared__ float Ts[(MODE == 2) ? 64 : 1][65];
    const int t  = threadIdx.x;
    const int tx = t & 15, ty = t >> 4;
    const int m0 = blockIdx.x * 64;
    const int n0 = blockIdx.y * 64;

    float acc[4][4] = {};

    for (int k0 = 0; k0 < 512; k0 += 32) {
        #pragma unroll
        for (int l = 0; l < 2; l++) {
            int qi = t + l * 256;
            int r = qi >> 3, q = qi & 7;
            float4 av = *reinterpret_cast<const float4*>(
                X + (size_t)(m0 + r) * 512 + k0 + q * 4);
            As[q * 4 + 0][r] = av.x; As[q * 4 + 1][r] = av.y;
            As[q * 4 + 2][r] = av.z; As[q * 4 + 3][r] = av.w;
        }
        #pragma unroll
        for (int l = 0; l < 2; l++) {
            int qi = t + l * 256;
            int kk = qi >> 4, q = qi & 15;
            *reinterpret_cast<float4*>(&Bs[kk][q * 4]) =
                *reinterpret_cast<const float4*>(
                    W + (size_t)(k0 + kk) * 512 + n0 + q * 4);
        }
        __syncthreads();
        #pragma unroll
        for (int kk = 0; kk < 32; kk++) {
            float4 a4 = *reinterpret_cast<const float4*>(&As[kk][ty * 4]);
            float4 b4 = *reinterpret_cast<const float4*>(&Bs[kk][tx * 4]);
            float av[4] = {a4.x, a4.y, a4.z, a4.w};
            float bv[4] = {b4.x, b4.y, b4.z, b4.w};
            #pragma unroll
            for (int ii = 0; ii < 4; ii++)
                #pragma unroll
                for (int jj = 0; jj < 4; jj++)
                    acc[ii][jj] = fmaf(av[ii], bv[jj], acc[ii][jj]);
        }
        __syncthreads();
    }

    if (MODE == 0) {
        const int h = n0 >> 6;
        #pragma unroll
        for (int ii = 0; ii < 4; ii++) {
            int m = m0 + ty * 4 + ii;
            int bb = m >> 10, nn = m & 1023;
            ushort4 o;
            o.x = f2b(acc[ii][0] * scale); o.y = f2b(acc[ii][1] * scale);
            o.z = f2b(acc[ii][2] * scale); o.w = f2b(acc[ii][3] * scale);
            *reinterpret_cast<ushort4*>(
                Ybf + ((size_t)((bb * 8 + h) * 1024 + nn)) * 64 + tx * 4) = o;
        }
    } else if (MODE == 1) {
        float4 bv = *reinterpret_cast<const float4*>(bias + n0 + tx * 4);
        #pragma unroll
        for (int ii = 0; ii < 4; ii++) {
            int m = m0 + ty * 4 + ii;
            float4 o;
            o.x = acc[ii][0] + bv.x; o.y = acc[ii][1] + bv.y;
            o.z = acc[ii][2] + bv.z; o.w = acc[ii][3] + bv.w;
            *reinterpret_cast<float4*>(Yf + (size_t)m * 512 + n0 + tx * 4) = o;
        }
    } else {
        #pragma unroll
        for (int ii = 0; ii < 4; ii++)
            #pragma unroll
            for (int jj = 0; jj < 4; jj++)
                Ts[ty * 4 + ii][tx * 4 + jj] = acc[ii][jj];
        __syncthreads();
        const int h = n0 >> 6;
        const int bb = m0 >> 10, nn = m0 & 1023;
        const int rc = t >> 2, jc = t & 3;
        unsigned short tmp[16];
        #pragma unroll
        for (int q = 0; q < 16; q++) tmp[q] = f2b(Ts[jc * 16 + q][rc]);
        unsigned short* dst = Ybf + (((size_t)(bb * 8 + h) * 64 + rc) << 10) + nn + jc * 16;
        *reinterpret_cast<short8*>(dst)     = *reinterpret_cast<short8*>(&tmp[0]);
        *reinterpret_cast<short8*>(dst + 8) = *reinterpret_cast<short8*>(&tmp[8]);
    }
}

// ---------------------------------------------------------------------------
// attn: grid 512 = b(2) x itile(64) x jsplit(4); 512 thr = 8 waves = heads.
// 2 blocks/CU — TLP hides staging & LDS latency; simple 4-barrier structure.
// ---------------------------------------------------------------------------
__global__ __launch_bounds__(512, 4) void attn_mfma(
    const unsigned short* __restrict__ qhg, const unsigned short* __restrict__ khg,
    const unsigned short* __restrict__ vtg, const float* __restrict__ rpb,
    const float* __restrict__ mask, float* __restrict__ xpart,
    float* __restrict__ lsump)
{
    __shared__ unsigned short rpb_s[16][16][72]; // [i][j][c]  36.9KB
    __shared__ unsigned short P[8][16][40];      // [h][i][j] j16..39 stay ZERO, 10.2KB
    __shared__ float S2s[16][8][17];             // [i][h][j]  8.7KB

    const int bid = blockIdx.x;
    const int js = bid & 3, it = (bid >> 2) & 63, b = bid >> 8;
    const int i0 = it * 16, jb = js * 256;
    const int t = threadIdx.x, w = t >> 6, l = t & 63;
    const int lg = l >> 4, l16 = l & 15;

    // staging map: per itr 0..3, thread covers (i = sib+4*itr, j = sj, c = sc..+7)
    const int sj = (t >> 3) & 15, sc = (t & 7) * 8, sib = t >> 7;
    const float* rpbb = rpb + ((size_t)(b * 1024 + i0) << 16);
    const unsigned short* khb = khg + ((size_t)(b * 8 + w) << 16);
    const unsigned short* vtb = vtg + ((size_t)(b * 8 + w) << 16);

    // ---- prologue: zero P pad, q fragments direct from global ----
    {
        unsigned short* P1 = &P[0][0][0];
        #pragma unroll
        for (int r = 0; r < 10; ++r) P1[t + 512 * r] = 0;   // 5120 = 512*10
    }
    short8 a1[2];   // S1 A-frag: q[w-head][i=l16][c=8lg+e (+32)]
    {
        const unsigned short* qp =
            qhg + (((size_t)(b * 8 + w) * 1024 + i0 + l16) << 6) + 8 * lg;
        a1[0] = *reinterpret_cast<const short8*>(qp);
        a1[1] = *reinterpret_cast<const short8*>(qp + 32);
    }
    float mrow[4];
    #pragma unroll
    for (int r = 0; r < 4; r++) mrow[r] = mask[b * 1024 + i0 + lg * 4 + r];

    const int jo = (lg < 2) ? 8 * lg : 0;   // clamp for zero-padded K half
    const int ro = jo;

    f32x4 x1[4];
    #pragma unroll
    for (int cs = 0; cs < 4; cs++) x1[cs] = 0.0f;
    f32x4 x2[2][4];
    #pragma unroll
    for (int il = 0; il < 2; il++)
        #pragma unroll
        for (int cg = 0; cg < 4; cg++) x2[il][cg] = 0.0f;
    float lsum[4] = {0.f, 0.f, 0.f, 0.f};

    for (int jt = 0; jt < 16; ++jt) {
        const int j0 = jb + jt * 16;
        __syncthreads();                         // barA: prev readers done

        // bq (S2 B-frag) reloaded per iter: q[head=l16&7][i=2w+il][c]
        short8 bq[2][2];
        #pragma unroll
        for (int il = 0; il < 2; ++il) {
            const unsigned short* qp =
                qhg + (((size_t)(b * 8 + (l16 & 7)) * 1024 + i0 + 2 * w + il) << 6) + 8 * lg;
            bq[il][0] = *reinterpret_cast<const short8*>(qp);
            bq[il][1] = *reinterpret_cast<const short8*>(qp + 32);
        }
        float mj = mask[b * 1024 + j0 + l16];

        // ---- stage rpb tile [16i][16j][64c] f32 -> bf16 (cvt_pk) ----
        #pragma unroll
        for (int itr = 0; itr < 4; ++itr) {
            const float4* s_ = reinterpret_cast<const float4*>(
                rpbb + ((size_t)(sib + 4 * itr) << 16) + (size_t)(j0 + sj) * 64 + sc);
            float4 ua = s_[0], ub = s_[1];
            uint4 pk;
            pk.x = cvt_pk(ua.x, ua.y); pk.y = cvt_pk(ua.z, ua.w);
            pk.z = cvt_pk(ub.x, ub.y); pk.w = cvt_pk(ub.z, ub.w);
            *reinterpret_cast<uint4*>(&rpb_s[sib + 4 * itr][sj][sc]) = pk;
        }
        __syncthreads();                         // barB: tile staged

        // ---- S1 = QK^T : D[16i x 16j], K=64 ----
        f32x4 C1; C1 = 0.0f;
        {
            const unsigned short* kp = khb + (((size_t)(j0 + l16)) << 6) + 8 * lg;
            short8 kb0 = *reinterpret_cast<const short8*>(kp);
            short8 kb1 = *reinterpret_cast<const short8*>(kp + 32);
            C1 = __builtin_amdgcn_mfma_f32_16x16x32_bf16(a1[0], kb0, C1, 0, 0, 0);
            C1 = __builtin_amdgcn_mfma_f32_16x16x32_bf16(a1[1], kb1, C1, 0, 0, 0);
        }
        // ---- S2^T = rpb(A) @ q(B) : D[16j x 8h] per i ----
        #pragma unroll
        for (int il = 0; il < 2; ++il) {
            int i = 2 * w + il;
            f32x4 D2; D2 = 0.0f;
            #pragma unroll
            for (int ch = 0; ch < 2; ++ch) {
                short8 ar = *reinterpret_cast<const short8*>(
                    &rpb_s[i][l16][ch * 32 + 8 * lg]);
                D2 = __builtin_amdgcn_mfma_f32_16x16x32_bf16(ar, bq[il][ch], D2, 0, 0, 0);
            }
            if (l16 < 8) {                        // D: row=j=4lg+r, col=h=l16
                #pragma unroll
                for (int r = 0; r < 4; ++r)
                    S2s[i][l16][4 * lg + r] = D2[r];
            }
        }
        __syncthreads();                         // barC: S2s ready

        // ---- P = exp(S1 + S2 + pairmask) ----
        #pragma unroll
        for (int r = 0; r < 4; ++r) {
            int ir = lg * 4 + r;
            float mi = mrow[r];
            float pm = (fmaxf(mi, mj) < 0.f) ? 0.f : fminf(mi, mj);
            float s = C1[r] + S2s[ir][w][l16] + pm;
            float p = __expf(s);                  // bounded logits; -1e4 -> 0
            lsum[r] += p;
            P[w][ir][l16] = f2b(p);
        }
        __syncthreads();                         // barD: P ready

        // ---- X1 += P @ vhT : D[16i x 64c] (upper K zero-padded) ----
        {
            short8 pa = *reinterpret_cast<const short8*>(&P[w][l16][8 * lg]);
            #pragma unroll
            for (int cs = 0; cs < 4; ++cs) {
                short8 vb = *reinterpret_cast<const short8*>(
                    vtb + ((size_t)(cs * 16 + l16) << 10) + j0 + jo);
                x1[cs] = __builtin_amdgcn_mfma_f32_16x16x32_bf16(pa, vb, x1[cs], 0, 0, 0);
            }
        }
        // ---- X2 += P(A) @ rpb(B) : D[8h x 16c] per i ----
        #pragma unroll
        for (int il = 0; il < 2; ++il) {
            int i = 2 * w + il;
            short8 pa2 = *reinterpret_cast<const short8*>(&P[l16 & 7][i][8 * lg]);
            #pragma unroll
            for (int cg = 0; cg < 4; ++cg) {
                short8 bb;
                #pragma unroll
                for (int e = 0; e < 8; ++e)
                    bb[e] = (short)rpb_s[i][ro + e][cg * 16 + l16];
                x2[il][cg] = __builtin_amdgcn_mfma_f32_16x16x32_bf16(pa2, bb, x2[il][cg], 0, 0, 0);
            }
        }
    }

    // ---- epilogue ----
    #pragma unroll
    for (int r = 0; r < 4; ++r) {
        float v = lsum[r];
        v += __shfl_xor(v, 1, 64); v += __shfl_xor(v, 2, 64);
        v += __shfl_xor(v, 4, 64); v += __shfl_xor(v, 8, 64);
        lsum[r] = v;
    }

    __syncthreads();   // all rpb_s reads done; reuse rpb_s as x2 redistribute buf
    float* x2s = reinterpret_cast<float*>(&rpb_s[0][0][0]);   // [16i][8h][64c]
    if (lg < 2) {
        #pragma unroll
        for (int il = 0; il < 2; ++il)
            #pragma unroll
            for (int cg = 0; cg < 4; ++cg)
                #pragma unroll
                for (int r = 0; r < 4; ++r)
                    x2s[((2 * w + il) * 8 + 4 * lg + r) * 64 + cg * 16 + l16] =
                        x2[il][cg][r];
    }
    __syncthreads();

    #pragma unroll
    for (int cs = 0; cs < 4; ++cs)
        #pragma unroll
        for (int r = 0; r < 4; ++r) {
            int ir = lg * 4 + r;
            float val = x1[cs][r] + x2s[(ir * 8 + w) * 64 + cs * 16 + l16];
            xpart[((size_t)js << 20) + ((size_t)(b * 1024 + i0 + ir)) * 512
                  + w * 64 + cs * 16 + l16] = val;
        }
    if (l16 == 0) {
        #pragma unroll
        for (int r = 0; r < 4; ++r)
            lsump[((size_t)js << 14) + (b * 8 + w) * 1024 + i0 + lg * 4 + r] = lsum[r];
    }
}

// ---------------------------------------------------------------------------
__global__ __launch_bounds__(256) void combine(
    const float* __restrict__ xpart, const float* __restrict__ lsump,
    float* __restrict__ xb)
{
    int idx4 = blockIdx.x * 256 + threadIdx.x;
    size_t base = (size_t)idx4 * 4;
    int row = (int)(base >> 9), col = (int)(base & 511);
    int bb = row >> 10, n = row & 1023, h = col >> 6;
    float ax = 0.f, ay = 0.f, az = 0.f, aw = 0.f, ls = 0.f;
    #pragma unroll
    for (int js = 0; js < 4; ++js) {
        float4 v = *reinterpret_cast<const float4*>(xpart + ((size_t)js << 20) + base);
        ax += v.x; ay += v.y; az += v.z; aw += v.w;
        ls += lsump[(js << 14) + (bb * 8 + h) * 1024 + n];
    }
    float inv = 1.f / ls;
    float4 o; o.x = ax * inv; o.y = ay * inv; o.z = az * inv; o.w = aw * inv;
    *reinterpret_cast<float4*>(xb + base) = o;
}

// ---------------------------------------------------------------------------
extern "C" void kernel_launch(void* const* d_in, const int* in_sizes, int n_in,
                              void* d_out, int out_size, void* d_ws, size_t ws_size,
                              hipStream_t stream)
{
    (void)in_sizes; (void)n_in; (void)out_size; (void)ws_size;
    const float* q    = (const float*)d_in[0];
    const float* k    = (const float*)d_in[1];
    const float* v    = (const float*)d_in[2];
    const float* rpb  = (const float*)d_in[3];
    const float* mask = (const float*)d_in[4];
    const float* Wq   = (const float*)d_in[5];
    const float* Wk   = (const float*)d_in[6];
    const float* Wv   = (const float*)d_in[7];
    const float* Wp   = (const float*)d_in[8];
    const float* bp   = (const float*)d_in[9];
    float* out = (float*)d_out;

    unsigned short* qhb = (unsigned short*)d_ws;     // bf16 [2,8,1024,64]
    unsigned short* khb = qhb + 1048576;
    unsigned short* vtb = khb + 1048576;             // bf16 [2,8,64,1024]
    float* xpart = (float*)(vtb + 1048576);          // [4][2048][512]
    float* lsump = xpart + 4194304;                  // [4][16384]
    float* xb    = lsump + 65536;                    // [2048][512]

    dim3 gg(32, 8, 1);
    gemm512<0><<<gg, 256, 0, stream>>>(q, Wq, nullptr, nullptr, qhb, 0.125f);
    gemm512<0><<<gg, 256, 0, stream>>>(k, Wk, nullptr, nullptr, khb, 1.0f);
    gemm512<2><<<gg, 256, 0, stream>>>(v, Wv, nullptr, nullptr, vtb, 1.0f);

    attn_mfma<<<512, 512, 0, stream>>>(qhb, khb, vtb, rpb, mask, xpart, lsump);

    combine<<<1024, 256, 0, stream>>>(xpart, lsump, xb);

    gemm512<1><<<gg, 256, 0, stream>>>(xb, Wp, bp, out, nullptr, 1.0f);
}